// Round 11
// baseline (155.164 us; speedup 1.0000x reference)
//
#include <hip/hip_runtime.h>
#include <stdint.h>

typedef unsigned short u16;
typedef __attribute__((ext_vector_type(8))) __bf16 bf16x8;
typedef __attribute__((ext_vector_type(4))) __bf16 bf16x4;
typedef __attribute__((ext_vector_type(4))) float f32x4;
typedef __attribute__((ext_vector_type(2))) unsigned int u32x2;
typedef __attribute__((ext_vector_type(4))) unsigned int u32x4;

#define QSCALE 0.18033688011112042f /* (1/8) * log2(e) */

__device__ __forceinline__ u16 f2bf(float f) {
    uint32_t u = __builtin_bit_cast(uint32_t, f);
    u = (u + 0x7fffu + ((u >> 16) & 1u)) >> 16;
    return (u16)u;
}

// async global->LDS, 16B/lane; LDS dest = wave-uniform base + lane*16.
__device__ __forceinline__ void gl_lds16(const u16* g, u16* l) {
    __builtin_amdgcn_global_load_lds(
        (__attribute__((address_space(1))) uint32_t*)(g),
        (__attribute__((address_space(3))) uint32_t*)(l), 16, 0, 0);
}

// counted-vmcnt barrier (T4): allow N newest DMAs to stay in flight across
// the barrier instead of __syncthreads' implicit vmcnt(0) drain.
__device__ __forceinline__ void cbar4() {
    asm volatile("s_waitcnt vmcnt(4)" ::: "memory");
    __builtin_amdgcn_s_barrier();
    __builtin_amdgcn_sched_barrier(0);
}
__device__ __forceinline__ void cbar3() {
    asm volatile("s_waitcnt vmcnt(3)" ::: "memory");
    __builtin_amdgcn_s_barrier();
    __builtin_amdgcn_sched_barrier(0);
}
__device__ __forceinline__ void cbar0() {
    asm volatile("s_waitcnt vmcnt(0)" ::: "memory");
    __builtin_amdgcn_s_barrier();
    __builtin_amdgcn_sched_barrier(0);
}

// ---- fused prep: x fp32->bf16 (blocks 0..4095) + wqkv transpose-cvt
// (blocks 4096..4287). wp transpose stays post-attn (wprojT aliases Qb).
__global__ __launch_bounds__(256) void prep_k(const float* __restrict__ xf,
                                              u16* __restrict__ xbf,
                                              const float* __restrict__ wq,
                                              u16* __restrict__ wqkvT) {
    __shared__ u16 t[64][65];
    const int b = blockIdx.x;
    const int tid = threadIdx.x;
    if (b < 4096) {
        const size_t v = (size_t)b * 256 + tid; // float4 index
        const f32x4 val = ((const f32x4*)xf)[v];
        u32x2 p;
        p.x = (uint32_t)f2bf(val.x) | ((uint32_t)f2bf(val.y) << 16);
        p.y = (uint32_t)f2bf(val.z) | ((uint32_t)f2bf(val.w) << 16);
        *(u32x2*)&xbf[v * 4] = p;
    } else {
        const int bb = b - 4096; // 24 x 8 tiles over [512][1536]
        const int bx = (bb % 24) << 6, by = (bb / 24) << 6;
        const int tx = tid & 63, ty = tid >> 6; // 64 x 4
#pragma unroll
        for (int i = ty; i < 64; i += 4)
            t[i][tx] = f2bf(wq[(size_t)(by + i) * 1536 + bx + tx]);
        __syncthreads();
#pragma unroll
        for (int i = ty; i < 64; i += 4)
            wqkvT[(size_t)(bx + i) * 512 + by + tx] = t[tx][i];
    }
}

// ---- weight transpose + cvt: in fp32[R][C] -> out bf16[C][R], 64x64 tiles ----
__global__ void transpose_cvt_k(const float* __restrict__ in,
                                u16* __restrict__ out, int R, int C) {
    __shared__ u16 t[64][65];
    const int bx = blockIdx.x << 6, by = blockIdx.y << 6;
    const int tx = threadIdx.x, ty = threadIdx.y; // 64 x 8
#pragma unroll
    for (int i = ty; i < 64; i += 8)
        t[i][tx] = f2bf(in[(size_t)(by + i) * C + bx + tx]);
    __syncthreads();
#pragma unroll
    for (int i = ty; i < 64; i += 8) out[(size_t)(bx + i) * R + by + tx] = t[tx][i];
}

// ---- MFMA GEMM, counted-vmcnt pipeline (T4): 3 staging buffers, stage 2
// ahead; per-iter barrier allows the newest stage's DMAs (4 for BN=128,
// 3 for BN=64) to stay in flight -- no vmcnt(0) drain in the K-loop
// (final iter excepted: no newer stage exists).
// EPI 0: LDS-bounce -> coalesced dwordx4 Q(xQSCALE)/K/Vt. EPI 1: fp32 direct.
template <int EPI, int BN>
__global__ __launch_bounds__(256, 3) void gemm_bt_k(
    const u16* __restrict__ A, const u16* __restrict__ Bt,
    const float* __restrict__ bias,
    u16* __restrict__ Qb, u16* __restrict__ Kb, u16* __restrict__ Vt,
    float* __restrict__ OutF) {
    constexpr int MI = (BN == 128) ? 4 : 2;
    constexpr int SSTG = 3 * 128 * 32 + 3 * BN * 32; // u16 units
    constexpr int SEPI = (EPI == 0) ? 128 * 136 : 0;
    constexpr int SMEM = SSTG > SEPI ? SSTG : SEPI;
    __shared__ u16 smem[SMEM];
    u16* lA = smem;                // [3][128*32]
    u16* lB = smem + 3 * 128 * 32; // [3][BN*32]

    const int tid = threadIdx.x;
    const int w = tid >> 6, l = tid & 63, quad = l >> 4, r = l & 15;
    const int tm = blockIdx.x << 7;
    const int tn = blockIdx.y * BN;
    const int wm = (BN == 128) ? ((w >> 1) << 6) : (w << 5);
    const int wn = (BN == 128) ? ((w & 1) << 6) : 0;
    const int srow = l >> 2, sch = (l & 3) << 3;

    f32x4 acc[MI][4];
#pragma unroll
    for (int i = 0; i < MI; ++i)
#pragma unroll
        for (int j = 0; j < 4; ++j) acc[i][j] = (f32x4){0.f, 0.f, 0.f, 0.f};

    auto stage = [&](int b, int kk) { // 4 (BN128) / 3 (BN64) DMAs per wave
#pragma unroll
        for (int ii = 0; ii < 2; ++ii) {
            const int rowl = w * 32 + ii * 16; // wave-uniform
            gl_lds16(A + (size_t)(tm + rowl + srow) * 512 + kk + sch,
                     &lA[b * 4096 + rowl * 32]);
        }
        if (BN == 128) {
#pragma unroll
            for (int ii = 0; ii < 2; ++ii) {
                const int rowl = w * 32 + ii * 16;
                gl_lds16(Bt + (size_t)(tn + rowl + srow) * 512 + kk + sch,
                         &lB[b * BN * 32 + rowl * 32]);
            }
        } else {
            const int rowl = w * 16;
            gl_lds16(Bt + (size_t)(tn + rowl + srow) * 512 + kk + sch,
                     &lB[b * BN * 32 + rowl * 32]);
        }
    };

    stage(0, 0);
    stage(1, 32);

    int cur = 0, nx1 = 1, nx2 = 2;
    for (int kk = 0; kk < 512; kk += 32) {
        // need tile t done; allow stage(t+1) in flight (exists iff kk<480)
        if (kk < 480) {
            if (BN == 128) cbar4(); else cbar3();
        } else {
            cbar0();
        }
        if (kk + 64 < 512) stage(nx2, kk + 64); // flies ~2 iters
        bf16x8 af[MI], bfr[4];
#pragma unroll
        for (int mi = 0; mi < MI; ++mi)
            af[mi] =
                *(const bf16x8*)&lA[cur * 4096 + (wm + mi * 16 + r) * 32 + quad * 8];
#pragma unroll
        for (int ni = 0; ni < 4; ++ni)
            bfr[ni] =
                *(const bf16x8*)&lB[cur * BN * 32 + (wn + ni * 16 + r) * 32 + quad * 8];
#pragma unroll
        for (int mi = 0; mi < MI; ++mi)
#pragma unroll
            for (int ni = 0; ni < 4; ++ni)
                acc[mi][ni] = __builtin_amdgcn_mfma_f32_16x16x32_bf16(
                    af[mi], bfr[ni], acc[mi][ni], 0, 0, 0);
        const int tmp = cur; cur = nx1; nx1 = nx2; nx2 = tmp;
    }

    if (EPI == 1) { // fp32 out, direct (64B runs, adequate)
#pragma unroll
        for (int ni = 0; ni < 4; ++ni) {
            const int n = tn + wn + ni * 16 + r;
            const float bv = bias[n];
#pragma unroll
            for (int mi = 0; mi < MI; ++mi)
#pragma unroll
                for (int i = 0; i < 4; ++i) {
                    const int m = tm + wm + mi * 16 + quad * 4 + i;
                    OutF[(size_t)m * 512 + n] = acc[mi][ni][i] + bv;
                }
        }
    } else {
        __syncthreads(); // all waves out of staging smem before epilogue reuse
        // ---- LDS-bounce epilogue: coalesced Q/K/Vt stores ----
        const bool isV = (tn >= 1024);
        const bool isQ = (tn < 512);
#pragma unroll
        for (int ni = 0; ni < 4; ++ni) {
            const int nl = wn + ni * 16 + r;
            const float bv = bias[tn + nl];
#pragma unroll
            for (int mi = 0; mi < MI; ++mi)
#pragma unroll
                for (int i = 0; i < 4; ++i) {
                    const int ml = wm + mi * 16 + quad * 4 + i;
                    float v = acc[mi][ni][i] + bv;
                    if (isQ) v *= QSCALE;
                    const u16 hb = f2bf(v);
                    if (isV)
                        smem[nl * 136 + ml] = hb; // transposed for t-contig rows
                    else
                        smem[ml * 136 + nl] = hb;
                }
        }
        __syncthreads();
        const int tbb = tm >> 11, tt = tm & 2047;
        if (!isV) {
            u16* base = isQ ? Qb : Kb;
            const int mlr = l >> 3, ls = l & 7;
#pragma unroll
            for (int rg = 0; rg < 4; ++rg)
#pragma unroll
                for (int h = 0; h < 2; ++h) {
                    const int ml = (w * 4 + rg) * 8 + mlr;
                    const int head = ((tn + h * 64) >> 6) & 7;
                    const int bh = tbb * 8 + head;
                    const u32x4 dv = *(const u32x4*)&smem[ml * 136 + h * 64 + ls * 8];
                    *(u32x4*)&base[((size_t)(bh * 2048 + tt + ml) << 6) + ls * 8] = dv;
                }
        } else {
            const int nlr = l >> 4, ls = l & 15;
#pragma unroll
            for (int j2 = 0; j2 < 8; ++j2) {
                const int nl = w * 32 + j2 * 4 + nlr;
                const int n = tn + nl;
                const int d = n & 63, head = (n >> 6) & 7;
                const int bh = tbb * 8 + head;
                const u32x4 dv = *(const u32x4*)&smem[nl * 136 + ls * 8];
                *(u32x4*)&Vt[((size_t)(bh * 64 + d) << 11) + tt + ls * 8] = dv;
            }
        }
    }
}

// ---- MFMA flash attention v10: v9 + counted-vmcnt barriers (T4).
// 4 K/V buffers, stage 3 ahead; per-iter vmcnt(4) lets the newest stage's
// 4 DMAs/wave cross the barrier (~2 iters of flight) -- __syncthreads'
// implicit vmcnt(0) drain was forcing staging onto the critical path every
// iter. Tail (t>=30): vmcnt(0) (no newer stage to exempt). K-frag register
// prefetch and in-register P path unchanged. LDS 64KB -> 2 blocks/CU.
__global__ __launch_bounds__(256, 2) void attn_k(
    const u16* __restrict__ Qb, const u16* __restrict__ Kb,
    const u16* __restrict__ Vt, u16* __restrict__ attnb) {
    __shared__ u16 lk[4][64 * 64];
    __shared__ u16 lv[4][64 * 64];
    const int tid = threadIdx.x;
    const int w = tid >> 6, l = tid & 63, quad = l >> 4, r = l & 15;
    const int qt = blockIdx.x, bh = blockIdx.y;
    const size_t qbase = (size_t)bh * 2048 + qt * 128;
    const int srl = l >> 3;
    const int sg = (l & 7) ^ srl; // V staging swizzle

    const int rl = r & 7;
    const int rhi = r >> 3;
    const int skq = (r & 3) ^ (((r >> 2) & 1) << 1) ^ (((r >> 2) & 2) << 1);
    const int g0 = (quad ^ skq) << 3; // stored granule (u16 units)

    bf16x8 qf[2][2];
#pragma unroll
    for (int qs = 0; qs < 2; ++qs)
#pragma unroll
        for (int hf = 0; hf < 2; ++hf)
            qf[qs][hf] = *(const bf16x8*)&Qb[((qbase + w * 32 + qs * 16 + r) << 6) +
                                            hf * 32 + quad * 8];

    const u32x4 onesu = {0x3F803F80u, 0x3F803F80u, 0x3F803F80u, 0x3F803F80u};
    const bf16x8 vones = __builtin_bit_cast(bf16x8, onesu); // bf16 1.0 x8

    f32x4 o[2][4];
#pragma unroll
    for (int qs = 0; qs < 2; ++qs)
#pragma unroll
        for (int i = 0; i < 4; ++i) o[qs][i] = (f32x4){0.f, 0.f, 0.f, 0.f};
    f32x4 osum[2];
    osum[0] = (f32x4){0.f, 0.f, 0.f, 0.f};
    osum[1] = (f32x4){0.f, 0.f, 0.f, 0.f};

    auto stage = [&](int b, int kv0) { // 4 DMAs per wave
#pragma unroll
        for (int ii = 0; ii < 2; ++ii) {
            const int chunk = w * 2 + ii;
            const int skr = (srl & 3) ^ ((chunk & 1) << 1) ^ ((chunk & 2) << 1);
            gl_lds16(Kb + ((size_t)(bh * 2048 + kv0 + chunk * 8 + srl) << 6) +
                         ((l & 7) ^ skr) * 8,
                     &lk[b][chunk * 512]);
            gl_lds16(Vt + (((size_t)(bh * 64 + chunk * 8 + srl)) << 11) + kv0 + sg * 8,
                     &lv[b][chunk * 512]);
        }
    };

    int Roff[4];
#pragma unroll
    for (int kt = 0; kt < 4; ++kt) {
        const int R = (kt & 1) * 32 + (r >> 2) * 8 + (kt >> 1) * 4 + (r & 3);
        Roff[kt] = R * 64 + g0;
    }

    auto readK = [&](int b, bf16x8 (&ka)[4], bf16x8 (&kb)[4]) {
        const u16* base = &lk[b][0];
#pragma unroll
        for (int kt = 0; kt < 4; ++kt) {
            ka[kt] = *(const bf16x8*)&base[Roff[kt]];
            kb[kt] = *(const bf16x8*)&base[Roff[kt] ^ 32];
        }
    };

    // prologue: stages 0,1,2 issued; need 0,1 done (readK(0) now, readK(1)
    // mid-iter-0); allow stage(2) to fly.
    stage(0, 0);
    stage(1, 64);
    stage(2, 128);
    cbar4();
    bf16x8 kaE[4], kbE[4], kaO[4], kbO[4];
    readK(0, kaE, kbE);

    int cur = 0, nx1 = 1, nx2 = 2, nx3 = 3;

    auto body = [&](int t, bf16x8 (&kaP)[4], bf16x8 (&kbP)[4],
                    bf16x8 (&kaN)[4], bf16x8 (&kbN)[4]) {
        // top-of-iter: need stage(t+1) done (mid-iter readK); allow
        // stage(t+2) in flight (exists iff t<30)
        if (t > 0) {
            if (t < 30) cbar4(); else cbar0();
        }
        if (t + 3 < 32) stage(nx3, (t + 3) * 64); // ~2 iters of flight
        bf16x8 vb[2][4];
#pragma unroll
        for (int h = 0; h < 2; ++h)
#pragma unroll
            for (int dt = 0; dt < 4; ++dt) {
                const int baseV = (dt * 2 + rhi) * 512 + rl * 64;
                vb[h][dt] = *(const bf16x8*)&lv[cur][baseV + ((h * 4 + quad) ^ rl) * 8];
            }
        // QK on prefetched K regs
        bf16x4 pk4[2][4];
#pragma unroll
        for (int kt = 0; kt < 4; ++kt) {
#pragma unroll
            for (int qs = 0; qs < 2; ++qs) {
                f32x4 z = (f32x4){0.f, 0.f, 0.f, 0.f};
                __builtin_amdgcn_s_setprio(1);
                z = __builtin_amdgcn_mfma_f32_16x16x32_bf16(kaP[kt], qf[qs][0], z, 0, 0, 0);
                z = __builtin_amdgcn_mfma_f32_16x16x32_bf16(kbP[kt], qf[qs][1], z, 0, 0, 0);
                __builtin_amdgcn_s_setprio(0);
                bf16x4 pb;
                pb[0] = (__bf16)__builtin_amdgcn_exp2f(z[0]);
                pb[1] = (__bf16)__builtin_amdgcn_exp2f(z[1]);
                pb[2] = (__bf16)__builtin_amdgcn_exp2f(z[2]);
                pb[3] = (__bf16)__builtin_amdgcn_exp2f(z[3]);
                pk4[qs][kt] = pb;
            }
        }
        // prefetch next iter's K-frags (tile t+1 guaranteed by top barrier)
        if (t + 1 < 32) readK(nx1, kaN, kbN);
        // PV
        __builtin_amdgcn_s_setprio(1);
#pragma unroll
        for (int h = 0; h < 2; ++h) {
            const bf16x8 ap0 = __builtin_shufflevector(pk4[0][h], pk4[0][h + 2],
                                                       0, 1, 2, 3, 4, 5, 6, 7);
            const bf16x8 ap1 = __builtin_shufflevector(pk4[1][h], pk4[1][h + 2],
                                                       0, 1, 2, 3, 4, 5, 6, 7);
#pragma unroll
            for (int dt = 0; dt < 4; ++dt) {
                o[0][dt] = __builtin_amdgcn_mfma_f32_16x16x32_bf16(ap0, vb[h][dt],
                                                                  o[0][dt], 0, 0, 0);
                o[1][dt] = __builtin_amdgcn_mfma_f32_16x16x32_bf16(ap1, vb[h][dt],
                                                                  o[1][dt], 0, 0, 0);
            }
            osum[0] = __builtin_amdgcn_mfma_f32_16x16x32_bf16(ap0, vones, osum[0], 0, 0, 0);
            osum[1] = __builtin_amdgcn_mfma_f32_16x16x32_bf16(ap1, vones, osum[1], 0, 0, 0);
        }
        __builtin_amdgcn_s_setprio(0);

        const int tmp = cur; cur = nx1; nx1 = nx2; nx2 = nx3; nx3 = tmp;
    };

    for (int t = 0; t < 32; t += 2) {
        body(t, kaE, kbE, kaO, kbO);
        body(t + 1, kaO, kbO, kaE, kbE);
    }

    const int bb = bh >> 3, head = bh & 7;
#pragma unroll
    for (int qs = 0; qs < 2; ++qs) {
#pragma unroll
        for (int i = 0; i < 4; ++i) {
            const float inv = __builtin_amdgcn_rcpf(osum[qs][i]); // <=1 ulp, fine
            const int row = bb * 2048 + qt * 128 + w * 32 + qs * 16 + quad * 4 + i;
#pragma unroll
            for (int dt = 0; dt < 4; ++dt)
                attnb[(size_t)row * 512 + head * 64 + dt * 16 + r] =
                    f2bf(o[qs][dt][i] * inv);
        }
    }
}

// ---------------- launch ----------------
extern "C" void kernel_launch(void* const* d_in, const int* in_sizes, int n_in,
                              void* d_out, int out_size, void* d_ws, size_t ws_size,
                              hipStream_t stream) {
    const float *x = nullptr, *wq = nullptr, *bq = nullptr, *wp = nullptr, *bp = nullptr;
    for (int i = 0; i < n_in; ++i) {
        switch (in_sizes[i]) {
            case 4194304: x  = (const float*)d_in[i]; break;
            case 786432:  wq = (const float*)d_in[i]; break;
            case 1536:    bq = (const float*)d_in[i]; break;
            case 262144:  wp = (const float*)d_in[i]; break;
            case 512:     bp = (const float*)d_in[i]; break;
        }
    }
    if (!x || !wq || !bq || !wp || !bp) {
        x = (const float*)d_in[0]; wq = (const float*)d_in[1];
        bq = (const float*)d_in[2]; wp = (const float*)d_in[3];
        bp = (const float*)d_in[4];
    }
    float* out = (float*)d_out;

    // ws plan (32 MiB): attnb@0 (wqkvT aliases until attn), Qb@8M (wprojT
    // aliases after attn), Kb@16M, Vt@24M. xbf lives in d_out until proj.
    char* ws = (char*)d_ws;
    u16* attnb  = (u16*)(ws + 0);
    u16* wqkvT  = (u16*)(ws + 0);
    u16* Qb     = (u16*)(ws + 8388608);
    u16* wprojT = (u16*)(ws + 8388608);
    u16* Kb     = (u16*)(ws + 16777216);
    u16* Vt     = (u16*)(ws + 25165824);
    u16* xbf    = (u16*)d_out;

    prep_k<<<dim3(4288), 256, 0, stream>>>(x, xbf, wq, wqkvT);
    gemm_bt_k<0, 128><<<dim3(64, 12), 256, 0, stream>>>(xbf, wqkvT, bq, Qb, Kb, Vt,
                                                        nullptr);
    attn_k<<<dim3(16, 32), 256, 0, stream>>>(Qb, Kb, Vt, attnb);
    transpose_cvt_k<<<dim3(8, 8), dim3(64, 8), 0, stream>>>(wp, wprojT, 512, 512);
    gemm_bt_k<1, 64><<<dim3(64, 8), 256, 0, stream>>>(attnb, wprojT, bp, nullptr,
                                                      nullptr, nullptr, out);
}

// Round 12
// 153.347 us; speedup vs baseline: 1.0118x; 1.0118x over previous
//
#include <hip/hip_runtime.h>
#include <stdint.h>

typedef unsigned short u16;
typedef __attribute__((ext_vector_type(8))) __bf16 bf16x8;
typedef __attribute__((ext_vector_type(4))) __bf16 bf16x4;
typedef __attribute__((ext_vector_type(4))) float f32x4;
typedef __attribute__((ext_vector_type(2))) unsigned int u32x2;
typedef __attribute__((ext_vector_type(4))) unsigned int u32x4;

#define QSCALE 0.18033688011112042f /* (1/8) * log2(e) */

__device__ __forceinline__ u16 f2bf(float f) {
    uint32_t u = __builtin_bit_cast(uint32_t, f);
    u = (u + 0x7fffu + ((u >> 16) & 1u)) >> 16;
    return (u16)u;
}

// async global->LDS, 16B/lane; LDS dest = wave-uniform base + lane*16.
__device__ __forceinline__ void gl_lds16(const u16* g, u16* l) {
    __builtin_amdgcn_global_load_lds(
        (__attribute__((address_space(1))) uint32_t*)(g),
        (__attribute__((address_space(3))) uint32_t*)(l), 16, 0, 0);
}

// ---- fused prep: x fp32->bf16 (blocks 0..4095) + wqkv transpose-cvt
// (blocks 4096..4287). No data reuse -> no XCD swizzle (T1 null here).
__global__ __launch_bounds__(256) void prep_k(const float* __restrict__ xf,
                                              u16* __restrict__ xbf,
                                              const float* __restrict__ wq,
                                              u16* __restrict__ wqkvT) {
    __shared__ u16 t[64][65];
    const int b = blockIdx.x;
    const int tid = threadIdx.x;
    if (b < 4096) {
        const size_t v = (size_t)b * 256 + tid; // float4 index
        const f32x4 val = ((const f32x4*)xf)[v];
        u32x2 p;
        p.x = (uint32_t)f2bf(val.x) | ((uint32_t)f2bf(val.y) << 16);
        p.y = (uint32_t)f2bf(val.z) | ((uint32_t)f2bf(val.w) << 16);
        *(u32x2*)&xbf[v * 4] = p;
    } else {
        const int bb = b - 4096; // 24 x 8 tiles over [512][1536]
        const int bx = (bb % 24) << 6, by = (bb / 24) << 6;
        const int tx = tid & 63, ty = tid >> 6; // 64 x 4
#pragma unroll
        for (int i = ty; i < 64; i += 4)
            t[i][tx] = f2bf(wq[(size_t)(by + i) * 1536 + bx + tx]);
        __syncthreads();
#pragma unroll
        for (int i = ty; i < 64; i += 4)
            wqkvT[(size_t)(bx + i) * 512 + by + tx] = t[tx][i];
    }
}

// ---- weight transpose + cvt: in fp32[R][C] -> out bf16[C][R], 64x64 tiles ----
__global__ void transpose_cvt_k(const float* __restrict__ in,
                                u16* __restrict__ out, int R, int C) {
    __shared__ u16 t[64][65];
    const int bx = blockIdx.x << 6, by = blockIdx.y << 6;
    const int tx = threadIdx.x, ty = threadIdx.y; // 64 x 8
#pragma unroll
    for (int i = ty; i < 64; i += 8)
        t[i][tx] = f2bf(in[(size_t)(by + i) * C + bx + tx]);
    __syncthreads();
#pragma unroll
    for (int i = ty; i < 64; i += 8) out[(size_t)(bx + i) * R + by + tx] = t[tx][i];
}

// ---- m97-style MFMA GEMM, 2-phase pipelined (proven R9/R10 loop) +
// T1 XCD-aware block swizzle: each XCD owns a contiguous M-chunk, tn
// fastest within it -> A-strips (12x/8x re-read) and the B-panel become
// L2-resident per XCD. Without this, consecutive blocks sharing operand
// panels round-robin across 8 non-coherent L2s: attn FETCH showed ~4x
// over-fetch from the same defect; gemm1's A was ~8x-fetched (~64MB).
// EPI 0: LDS-bounce -> coalesced dwordx4 Q(xQSCALE)/K/Vt. EPI 1: fp32 direct.
template <int EPI, int BN>
__global__ __launch_bounds__(256, 3) void gemm_bt_k(
    const u16* __restrict__ A, const u16* __restrict__ Bt,
    const float* __restrict__ bias,
    u16* __restrict__ Qb, u16* __restrict__ Kb, u16* __restrict__ Vt,
    float* __restrict__ OutF) {
    constexpr int MI = (BN == 128) ? 4 : 2;
    constexpr int NT = (BN == 128) ? 12 : 8; // tn tiles (grid y)
    constexpr int SSTG = 2 * 128 * 32 + 2 * BN * 32; // u16 units
    constexpr int SEPI = (EPI == 0) ? 128 * 136 : 0;
    constexpr int SMEM = SSTG > SEPI ? SSTG : SEPI;
    __shared__ u16 smem[SMEM];
    u16* lA = smem;                // [2][128*32]
    u16* lB = smem + 2 * 128 * 32; // [2][BN*32]

    const int tid = threadIdx.x;
    const int w = tid >> 6, l = tid & 63, quad = l >> 4, r = l & 15;
    // XCD swizzle: 64 M-tiles over 8 XCDs; tn fastest within an XCD.
    const int bid = blockIdx.x + 64 * blockIdx.y; // [0, 64*NT)
    const int xcd = bid & 7, idx = bid >> 3;      // idx in [0, 8*NT)
    const int tm = (xcd * 8 + idx / NT) << 7;
    const int tn = (idx % NT) * BN;
    const int wm = (BN == 128) ? ((w >> 1) << 6) : (w << 5);
    const int wn = (BN == 128) ? ((w & 1) << 6) : 0;
    const int srow = l >> 2, sch = (l & 3) << 3;

    f32x4 acc[MI][4];
#pragma unroll
    for (int i = 0; i < MI; ++i)
#pragma unroll
        for (int j = 0; j < 4; ++j) acc[i][j] = (f32x4){0.f, 0.f, 0.f, 0.f};

    auto stage = [&](int b, int kk) {
#pragma unroll
        for (int ii = 0; ii < 2; ++ii) {
            const int rowl = w * 32 + ii * 16; // wave-uniform
            gl_lds16(A + (size_t)(tm + rowl + srow) * 512 + kk + sch,
                     &lA[b * 4096 + rowl * 32]);
        }
        if (BN == 128) {
#pragma unroll
            for (int ii = 0; ii < 2; ++ii) {
                const int rowl = w * 32 + ii * 16;
                gl_lds16(Bt + (size_t)(tn + rowl + srow) * 512 + kk + sch,
                         &lB[b * BN * 32 + rowl * 32]);
            }
        } else {
            const int rowl = w * 16;
            gl_lds16(Bt + (size_t)(tn + rowl + srow) * 512 + kk + sch,
                     &lB[b * BN * 32 + rowl * 32]);
        }
    };

    stage(0, 0);
    __syncthreads(); // implicit vmcnt(0): tile 0 resident

    int cur = 0;
    for (int kk = 0; kk < 512; kk += 32) {
        if (kk + 32 < 512) stage(cur ^ 1, kk + 32); // in flight during compute
        bf16x8 af[MI], bfr[4];
#pragma unroll
        for (int mi = 0; mi < MI; ++mi)
            af[mi] =
                *(const bf16x8*)&lA[cur * 4096 + (wm + mi * 16 + r) * 32 + quad * 8];
#pragma unroll
        for (int ni = 0; ni < 4; ++ni)
            bfr[ni] =
                *(const bf16x8*)&lB[cur * BN * 32 + (wn + ni * 16 + r) * 32 + quad * 8];
#pragma unroll
        for (int mi = 0; mi < MI; ++mi)
#pragma unroll
            for (int ni = 0; ni < 4; ++ni)
                acc[mi][ni] = __builtin_amdgcn_mfma_f32_16x16x32_bf16(
                    af[mi], bfr[ni], acc[mi][ni], 0, 0, 0);
        __syncthreads(); // drains next-tile loads (flew during MFMAs) + frag reads
        cur ^= 1;
    }

    if (EPI == 1) { // fp32 out, direct (64B runs, adequate)
#pragma unroll
        for (int ni = 0; ni < 4; ++ni) {
            const int n = tn + wn + ni * 16 + r;
            const float bv = bias[n];
#pragma unroll
            for (int mi = 0; mi < MI; ++mi)
#pragma unroll
                for (int i = 0; i < 4; ++i) {
                    const int m = tm + wm + mi * 16 + quad * 4 + i;
                    OutF[(size_t)m * 512 + n] = acc[mi][ni][i] + bv;
                }
        }
    } else {
        // ---- LDS-bounce epilogue: coalesced Q/K/Vt stores ----
        const bool isV = (tn >= 1024);
        const bool isQ = (tn < 512);
#pragma unroll
        for (int ni = 0; ni < 4; ++ni) {
            const int nl = wn + ni * 16 + r;
            const float bv = bias[tn + nl];
#pragma unroll
            for (int mi = 0; mi < MI; ++mi)
#pragma unroll
                for (int i = 0; i < 4; ++i) {
                    const int ml = wm + mi * 16 + quad * 4 + i;
                    float v = acc[mi][ni][i] + bv;
                    if (isQ) v *= QSCALE;
                    const u16 hb = f2bf(v);
                    if (isV)
                        smem[nl * 136 + ml] = hb; // transposed for t-contig rows
                    else
                        smem[ml * 136 + nl] = hb;
                }
        }
        __syncthreads();
        const int tbb = tm >> 11, tt = tm & 2047;
        if (!isV) {
            u16* base = isQ ? Qb : Kb;
            const int mlr = l >> 3, ls = l & 7;
#pragma unroll
            for (int rg = 0; rg < 4; ++rg)
#pragma unroll
                for (int h = 0; h < 2; ++h) {
                    const int ml = (w * 4 + rg) * 8 + mlr;
                    const int head = ((tn + h * 64) >> 6) & 7;
                    const int bh = tbb * 8 + head;
                    const u32x4 dv = *(const u32x4*)&smem[ml * 136 + h * 64 + ls * 8];
                    *(u32x4*)&base[((size_t)(bh * 2048 + tt + ml) << 6) + ls * 8] = dv;
                }
        } else {
            const int nlr = l >> 4, ls = l & 15;
#pragma unroll
            for (int j2 = 0; j2 < 8; ++j2) {
                const int nl = w * 32 + j2 * 4 + nlr;
                const int n = tn + nl;
                const int d = n & 63, head = (n >> 6) & 7;
                const int bh = tbb * 8 + head;
                const u32x4 dv = *(const u32x4*)&smem[nl * 136 + ls * 8];
                *(u32x4*)&Vt[((size_t)(bh * 64 + d) << 11) + tt + ls * 8] = dv;
            }
        }
    }
}

// ---- MFMA flash attention v11: R10's best structure (3 buffers, stage 2
// ahead, cross-barrier K-frag register prefetch, in-register P path, zero
// bank conflicts) + T1 XCD swizzle: each XCD owns 4 bh (2MB K/V, L2-fits),
// so the 16 qt-blocks sharing one bh's K/V hit the same L2 instead of
// fetching it from HBM on up to 8 XCDs (FETCH 69.7MB vs ~25MB compulsory).
__global__ __launch_bounds__(256, 2) void attn_k(
    const u16* __restrict__ Qb, const u16* __restrict__ Kb,
    const u16* __restrict__ Vt, u16* __restrict__ attnb) {
    __shared__ u16 lk[3][64 * 64];
    __shared__ u16 lv[3][64 * 64];
    const int tid = threadIdx.x;
    const int w = tid >> 6, l = tid & 63, quad = l >> 4, r = l & 15;
    // XCD swizzle: bh-chunk per XCD, qt fastest.
    const int bid = blockIdx.x + 16 * blockIdx.y; // [0,512)
    const int xcd = bid & 7, idx = bid >> 3;      // idx in [0,64)
    const int bh = xcd * 4 + (idx >> 4);
    const int qt = idx & 15;
    const size_t qbase = (size_t)bh * 2048 + qt * 128;
    const int srl = l >> 3;
    const int sg = (l & 7) ^ srl; // V staging swizzle

    const int rl = r & 7;
    const int rhi = r >> 3;
    const int skq = (r & 3) ^ (((r >> 2) & 1) << 1) ^ (((r >> 2) & 2) << 1);
    const int g0 = (quad ^ skq) << 3; // stored granule (u16 units)

    bf16x8 qf[2][2];
#pragma unroll
    for (int qs = 0; qs < 2; ++qs)
#pragma unroll
        for (int hf = 0; hf < 2; ++hf)
            qf[qs][hf] = *(const bf16x8*)&Qb[((qbase + w * 32 + qs * 16 + r) << 6) +
                                            hf * 32 + quad * 8];

    const u32x4 onesu = {0x3F803F80u, 0x3F803F80u, 0x3F803F80u, 0x3F803F80u};
    const bf16x8 vones = __builtin_bit_cast(bf16x8, onesu); // bf16 1.0 x8

    f32x4 o[2][4];
#pragma unroll
    for (int qs = 0; qs < 2; ++qs)
#pragma unroll
        for (int i = 0; i < 4; ++i) o[qs][i] = (f32x4){0.f, 0.f, 0.f, 0.f};
    f32x4 osum[2];
    osum[0] = (f32x4){0.f, 0.f, 0.f, 0.f};
    osum[1] = (f32x4){0.f, 0.f, 0.f, 0.f};

    auto stage = [&](int b, int kv0) {
#pragma unroll
        for (int ii = 0; ii < 2; ++ii) {
            const int chunk = w * 2 + ii;
            const int skr = (srl & 3) ^ ((chunk & 1) << 1) ^ ((chunk & 2) << 1);
            gl_lds16(Kb + ((size_t)(bh * 2048 + kv0 + chunk * 8 + srl) << 6) +
                         ((l & 7) ^ skr) * 8,
                     &lk[b][chunk * 512]);
            gl_lds16(Vt + (((size_t)(bh * 64 + chunk * 8 + srl)) << 11) + kv0 + sg * 8,
                     &lv[b][chunk * 512]);
        }
    };

    int Roff[4];
#pragma unroll
    for (int kt = 0; kt < 4; ++kt) {
        const int R = (kt & 1) * 32 + (r >> 2) * 8 + (kt >> 1) * 4 + (r & 3);
        Roff[kt] = R * 64 + g0;
    }

    auto readK = [&](int b, bf16x8 (&ka)[4], bf16x8 (&kb)[4]) {
        const u16* base = &lk[b][0];
#pragma unroll
        for (int kt = 0; kt < 4; ++kt) {
            ka[kt] = *(const bf16x8*)&base[Roff[kt]];
            kb[kt] = *(const bf16x8*)&base[Roff[kt] ^ 32];
        }
    };

    stage(0, 0);
    stage(1, 64);
    __syncthreads(); // tiles 0,1 resident

    bf16x8 kaE[4], kbE[4], kaO[4], kbO[4]; // even/odd iter K-frag sets
    readK(0, kaE, kbE);

    int cur = 0, nx1 = 1, nx2 = 2;

    auto body = [&](int t, bf16x8 (&kaP)[4], bf16x8 (&kbP)[4],
                    bf16x8 (&kaN)[4], bf16x8 (&kbN)[4]) {
        if (t + 2 < 32) stage(nx2, (t + 2) * 64); // DMA flies under compute
        bf16x8 vb[2][4];
#pragma unroll
        for (int h = 0; h < 2; ++h)
#pragma unroll
            for (int dt = 0; dt < 4; ++dt) {
                const int baseV = (dt * 2 + rhi) * 512 + rl * 64;
                vb[h][dt] = *(const bf16x8*)&lv[cur][baseV + ((h * 4 + quad) ^ rl) * 8];
            }
        // QK on PREFETCHED K-frags: starts immediately post-barrier
        bf16x4 pk4[2][4];
#pragma unroll
        for (int kt = 0; kt < 4; ++kt) {
#pragma unroll
            for (int qs = 0; qs < 2; ++qs) {
                f32x4 z = (f32x4){0.f, 0.f, 0.f, 0.f};
                __builtin_amdgcn_s_setprio(1);
                z = __builtin_amdgcn_mfma_f32_16x16x32_bf16(kaP[kt], qf[qs][0], z, 0, 0, 0);
                z = __builtin_amdgcn_mfma_f32_16x16x32_bf16(kbP[kt], qf[qs][1], z, 0, 0, 0);
                __builtin_amdgcn_s_setprio(0);
                bf16x4 pb;
                pb[0] = (__bf16)__builtin_amdgcn_exp2f(z[0]);
                pb[1] = (__bf16)__builtin_amdgcn_exp2f(z[1]);
                pb[2] = (__bf16)__builtin_amdgcn_exp2f(z[2]);
                pb[3] = (__bf16)__builtin_amdgcn_exp2f(z[3]);
                pk4[qs][kt] = pb;
            }
        }
        // prefetch NEXT iter's K-frags (tile t+1 drained at last barrier)
        if (t + 1 < 32) readK(nx1, kaN, kbN);
        // PV
        __builtin_amdgcn_s_setprio(1);
#pragma unroll
        for (int h = 0; h < 2; ++h) {
            const bf16x8 ap0 = __builtin_shufflevector(pk4[0][h], pk4[0][h + 2],
                                                       0, 1, 2, 3, 4, 5, 6, 7);
            const bf16x8 ap1 = __builtin_shufflevector(pk4[1][h], pk4[1][h + 2],
                                                       0, 1, 2, 3, 4, 5, 6, 7);
#pragma unroll
            for (int dt = 0; dt < 4; ++dt) {
                o[0][dt] = __builtin_amdgcn_mfma_f32_16x16x32_bf16(ap0, vb[h][dt],
                                                                  o[0][dt], 0, 0, 0);
                o[1][dt] = __builtin_amdgcn_mfma_f32_16x16x32_bf16(ap1, vb[h][dt],
                                                                  o[1][dt], 0, 0, 0);
            }
            osum[0] = __builtin_amdgcn_mfma_f32_16x16x32_bf16(ap0, vones, osum[0], 0, 0, 0);
            osum[1] = __builtin_amdgcn_mfma_f32_16x16x32_bf16(ap1, vones, osum[1], 0, 0, 0);
        }
        __builtin_amdgcn_s_setprio(0);

        __syncthreads(); // drains stage(t+2); tile t+1 already long-resident
        const int tmp = cur;
        cur = nx1;
        nx1 = nx2;
        nx2 = tmp;
    };

    for (int t = 0; t < 32; t += 2) {
        body(t, kaE, kbE, kaO, kbO);
        body(t + 1, kaO, kbO, kaE, kbE);
    }

    const int bb = bh >> 3, head = bh & 7;
#pragma unroll
    for (int qs = 0; qs < 2; ++qs) {
#pragma unroll
        for (int i = 0; i < 4; ++i) {
            const float inv = __builtin_amdgcn_rcpf(osum[qs][i]); // <=1 ulp, fine
            const int row = bb * 2048 + qt * 128 + w * 32 + qs * 16 + quad * 4 + i;
#pragma unroll
            for (int dt = 0; dt < 4; ++dt)
                attnb[(size_t)row * 512 + head * 64 + dt * 16 + r] =
                    f2bf(o[qs][dt][i] * inv);
        }
    }
}

// ---------------- launch ----------------
extern "C" void kernel_launch(void* const* d_in, const int* in_sizes, int n_in,
                              void* d_out, int out_size, void* d_ws, size_t ws_size,
                              hipStream_t stream) {
    const float *x = nullptr, *wq = nullptr, *bq = nullptr, *wp = nullptr, *bp = nullptr;
    for (int i = 0; i < n_in; ++i) {
        switch (in_sizes[i]) {
            case 4194304: x  = (const float*)d_in[i]; break;
            case 786432:  wq = (const float*)d_in[i]; break;
            case 1536:    bq = (const float*)d_in[i]; break;
            case 262144:  wp = (const float*)d_in[i]; break;
            case 512:     bp = (const float*)d_in[i]; break;
        }
    }
    if (!x || !wq || !bq || !wp || !bp) {
        x = (const float*)d_in[0]; wq = (const float*)d_in[1];
        bq = (const float*)d_in[2]; wp = (const float*)d_in[3];
        bp = (const float*)d_in[4];
    }
    float* out = (float*)d_out;

    // ws plan (32 MiB): attnb@0 (wqkvT aliases until attn), Qb@8M (wprojT
    // aliases after attn), Kb@16M, Vt@24M. xbf lives in d_out until proj.
    char* ws = (char*)d_ws;
    u16* attnb  = (u16*)(ws + 0);
    u16* wqkvT  = (u16*)(ws + 0);
    u16* Qb     = (u16*)(ws + 8388608);
    u16* wprojT = (u16*)(ws + 8388608);
    u16* Kb     = (u16*)(ws + 16777216);
    u16* Vt     = (u16*)(ws + 25165824);
    u16* xbf    = (u16*)d_out;

    prep_k<<<dim3(4288), 256, 0, stream>>>(x, xbf, wq, wqkvT);
    gemm_bt_k<0, 128><<<dim3(64, 12), 256, 0, stream>>>(xbf, wqkvT, bq, Qb, Kb, Vt,
                                                        nullptr);
    attn_k<<<dim3(16, 32), 256, 0, stream>>>(Qb, Kb, Vt, attnb);
    transpose_cvt_k<<<dim3(8, 8), dim3(64, 8), 0, stream>>>(wp, wprojT, 512, 512);
    gemm_bt_k<1, 64><<<dim3(64, 8), 256, 0, stream>>>(attnb, wprojT, bp, nullptr,
                                                      nullptr, nullptr, out);
}

// Round 13
// 151.258 us; speedup vs baseline: 1.0258x; 1.0138x over previous
//
#include <hip/hip_runtime.h>
#include <stdint.h>

typedef unsigned short u16;
typedef __attribute__((ext_vector_type(8))) __bf16 bf16x8;
typedef __attribute__((ext_vector_type(4))) __bf16 bf16x4;
typedef __attribute__((ext_vector_type(4))) float f32x4;
typedef __attribute__((ext_vector_type(2))) unsigned int u32x2;
typedef __attribute__((ext_vector_type(4))) unsigned int u32x4;

#define QSCALE 0.18033688011112042f /* (1/8) * log2(e) */

__device__ __forceinline__ u16 f2bf(float f) {
    uint32_t u = __builtin_bit_cast(uint32_t, f);
    u = (u + 0x7fffu + ((u >> 16) & 1u)) >> 16;
    return (u16)u;
}

// async global->LDS, 16B/lane; LDS dest = wave-uniform base + lane*16.
__device__ __forceinline__ void gl_lds16(const u16* g, u16* l) {
    __builtin_amdgcn_global_load_lds(
        (__attribute__((address_space(1))) uint32_t*)(g),
        (__attribute__((address_space(3))) uint32_t*)(l), 16, 0, 0);
}

// ---- fused prep (one launch, 3 jobs):
//   blocks [0,4096):      x fp32 -> bf16
//   blocks [4096,4288):   wqkv transpose-cvt (24x8 tiles over [512][1536])
//   blocks [4288,4352):   wp transpose-cvt   (8x8  tiles over [512][512])
// wprojT lives at ws+32MiB (ws=256MiB per the harness's 256MiB re-poison
// fill), so it no longer aliases Qb and can be produced up front.
__global__ __launch_bounds__(256) void prep_k(const float* __restrict__ xf,
                                              u16* __restrict__ xbf,
                                              const float* __restrict__ wq,
                                              u16* __restrict__ wqkvT,
                                              const float* __restrict__ wp,
                                              u16* __restrict__ wprojT) {
    __shared__ u16 t[64][65];
    const int b = blockIdx.x;
    const int tid = threadIdx.x;
    if (b < 4096) {
        const size_t v = (size_t)b * 256 + tid; // float4 index
        const f32x4 val = ((const f32x4*)xf)[v];
        u32x2 p;
        p.x = (uint32_t)f2bf(val.x) | ((uint32_t)f2bf(val.y) << 16);
        p.y = (uint32_t)f2bf(val.z) | ((uint32_t)f2bf(val.w) << 16);
        *(u32x2*)&xbf[v * 4] = p;
    } else {
        const bool isWq = (b < 4288);
        const int bb = isWq ? (b - 4096) : (b - 4288);
        const int nbx = isWq ? 24 : 8;
        const int C = isWq ? 1536 : 512;
        const float* src = isWq ? wq : wp;
        u16* dst = isWq ? wqkvT : wprojT;
        const int bx = (bb % nbx) << 6, by = (bb / nbx) << 6;
        const int tx = tid & 63, ty = tid >> 6; // 64 x 4
#pragma unroll
        for (int i = ty; i < 64; i += 4)
            t[i][tx] = f2bf(src[(size_t)(by + i) * C + bx + tx]);
        __syncthreads();
#pragma unroll
        for (int i = ty; i < 64; i += 4)
            dst[(size_t)(bx + i) * 512 + by + tx] = t[tx][i];
    }
}

// ---- m97-style MFMA GEMM, 2-phase pipelined (R10 best-measured config:
// plain blockIdx mapping -- R12's XCD swizzle was neutral-to-negative here).
// EPI 0: LDS-bounce -> coalesced dwordx4 Q(xQSCALE)/K/Vt. EPI 1: fp32 direct.
template <int EPI, int BN>
__global__ __launch_bounds__(256, 3) void gemm_bt_k(
    const u16* __restrict__ A, const u16* __restrict__ Bt,
    const float* __restrict__ bias,
    u16* __restrict__ Qb, u16* __restrict__ Kb, u16* __restrict__ Vt,
    float* __restrict__ OutF) {
    constexpr int MI = (BN == 128) ? 4 : 2;
    constexpr int SSTG = 2 * 128 * 32 + 2 * BN * 32; // u16 units
    constexpr int SEPI = (EPI == 0) ? 128 * 136 : 0;
    constexpr int SMEM = SSTG > SEPI ? SSTG : SEPI;
    __shared__ u16 smem[SMEM];
    u16* lA = smem;                // [2][128*32]
    u16* lB = smem + 2 * 128 * 32; // [2][BN*32]

    const int tid = threadIdx.x;
    const int w = tid >> 6, l = tid & 63, quad = l >> 4, r = l & 15;
    const int tm = blockIdx.x << 7;
    const int tn = blockIdx.y * BN;
    const int wm = (BN == 128) ? ((w >> 1) << 6) : (w << 5);
    const int wn = (BN == 128) ? ((w & 1) << 6) : 0;
    const int srow = l >> 2, sch = (l & 3) << 3;

    f32x4 acc[MI][4];
#pragma unroll
    for (int i = 0; i < MI; ++i)
#pragma unroll
        for (int j = 0; j < 4; ++j) acc[i][j] = (f32x4){0.f, 0.f, 0.f, 0.f};

    auto stage = [&](int b, int kk) {
#pragma unroll
        for (int ii = 0; ii < 2; ++ii) {
            const int rowl = w * 32 + ii * 16; // wave-uniform
            gl_lds16(A + (size_t)(tm + rowl + srow) * 512 + kk + sch,
                     &lA[b * 4096 + rowl * 32]);
        }
        if (BN == 128) {
#pragma unroll
            for (int ii = 0; ii < 2; ++ii) {
                const int rowl = w * 32 + ii * 16;
                gl_lds16(Bt + (size_t)(tn + rowl + srow) * 512 + kk + sch,
                         &lB[b * BN * 32 + rowl * 32]);
            }
        } else {
            const int rowl = w * 16;
            gl_lds16(Bt + (size_t)(tn + rowl + srow) * 512 + kk + sch,
                     &lB[b * BN * 32 + rowl * 32]);
        }
    };

    stage(0, 0);
    __syncthreads(); // implicit vmcnt(0): tile 0 resident

    int cur = 0;
    for (int kk = 0; kk < 512; kk += 32) {
        if (kk + 32 < 512) stage(cur ^ 1, kk + 32); // in flight during compute
        bf16x8 af[MI], bfr[4];
#pragma unroll
        for (int mi = 0; mi < MI; ++mi)
            af[mi] =
                *(const bf16x8*)&lA[cur * 4096 + (wm + mi * 16 + r) * 32 + quad * 8];
#pragma unroll
        for (int ni = 0; ni < 4; ++ni)
            bfr[ni] =
                *(const bf16x8*)&lB[cur * BN * 32 + (wn + ni * 16 + r) * 32 + quad * 8];
#pragma unroll
        for (int mi = 0; mi < MI; ++mi)
#pragma unroll
            for (int ni = 0; ni < 4; ++ni)
                acc[mi][ni] = __builtin_amdgcn_mfma_f32_16x16x32_bf16(
                    af[mi], bfr[ni], acc[mi][ni], 0, 0, 0);
        __syncthreads(); // drains next-tile loads (flew during MFMAs) + frag reads
        cur ^= 1;
    }

    if (EPI == 1) { // fp32 out, direct (64B aligned 64B runs = full sectors)
#pragma unroll
        for (int ni = 0; ni < 4; ++ni) {
            const int n = tn + wn + ni * 16 + r;
            const float bv = bias[n];
#pragma unroll
            for (int mi = 0; mi < MI; ++mi)
#pragma unroll
                for (int i = 0; i < 4; ++i) {
                    const int m = tm + wm + mi * 16 + quad * 4 + i;
                    OutF[(size_t)m * 512 + n] = acc[mi][ni][i] + bv;
                }
        }
    } else {
        // ---- LDS-bounce epilogue: coalesced Q/K/Vt stores ----
        const bool isV = (tn >= 1024);
        const bool isQ = (tn < 512);
#pragma unroll
        for (int ni = 0; ni < 4; ++ni) {
            const int nl = wn + ni * 16 + r;
            const float bv = bias[tn + nl];
#pragma unroll
            for (int mi = 0; mi < MI; ++mi)
#pragma unroll
                for (int i = 0; i < 4; ++i) {
                    const int ml = wm + mi * 16 + quad * 4 + i;
                    float v = acc[mi][ni][i] + bv;
                    if (isQ) v *= QSCALE;
                    const u16 hb = f2bf(v);
                    if (isV)
                        smem[nl * 136 + ml] = hb; // transposed for t-contig rows
                    else
                        smem[ml * 136 + nl] = hb;
                }
        }
        __syncthreads();
        const int tbb = tm >> 11, tt = tm & 2047;
        if (!isV) {
            u16* base = isQ ? Qb : Kb;
            const int mlr = l >> 3, ls = l & 7;
#pragma unroll
            for (int rg = 0; rg < 4; ++rg)
#pragma unroll
                for (int h = 0; h < 2; ++h) {
                    const int ml = (w * 4 + rg) * 8 + mlr;
                    const int head = ((tn + h * 64) >> 6) & 7;
                    const int bh = tbb * 8 + head;
                    const u32x4 dv = *(const u32x4*)&smem[ml * 136 + h * 64 + ls * 8];
                    *(u32x4*)&base[((size_t)(bh * 2048 + tt + ml) << 6) + ls * 8] = dv;
                }
        } else {
            const int nlr = l >> 4, ls = l & 15;
#pragma unroll
            for (int j2 = 0; j2 < 8; ++j2) {
                const int nl = w * 32 + j2 * 4 + nlr;
                const int n = tn + nl;
                const int d = n & 63, head = (n >> 6) & 7;
                const int bh = tbb * 8 + head;
                const u32x4 dv = *(const u32x4*)&smem[nl * 136 + ls * 8];
                *(u32x4*)&Vt[((size_t)(bh * 64 + d) << 11) + tt + ls * 8] = dv;
            }
        }
    }
}

// ---- MFMA flash attention v11 (frozen from R12): 3 buffers, stage 2
// ahead, cross-barrier K-frag register prefetch, in-register P path, zero
// bank conflicts, XCD swizzle (each XCD owns 4 bh -> 2MB K/V L2-resident).
__global__ __launch_bounds__(256, 2) void attn_k(
    const u16* __restrict__ Qb, const u16* __restrict__ Kb,
    const u16* __restrict__ Vt, u16* __restrict__ attnb) {
    __shared__ u16 lk[3][64 * 64];
    __shared__ u16 lv[3][64 * 64];
    const int tid = threadIdx.x;
    const int w = tid >> 6, l = tid & 63, quad = l >> 4, r = l & 15;
    // XCD swizzle: bh-chunk per XCD, qt fastest.
    const int bid = blockIdx.x + 16 * blockIdx.y; // [0,512)
    const int xcd = bid & 7, idx = bid >> 3;      // idx in [0,64)
    const int bh = xcd * 4 + (idx >> 4);
    const int qt = idx & 15;
    const size_t qbase = (size_t)bh * 2048 + qt * 128;
    const int srl = l >> 3;
    const int sg = (l & 7) ^ srl; // V staging swizzle

    const int rl = r & 7;
    const int rhi = r >> 3;
    const int skq = (r & 3) ^ (((r >> 2) & 1) << 1) ^ (((r >> 2) & 2) << 1);
    const int g0 = (quad ^ skq) << 3; // stored granule (u16 units)

    bf16x8 qf[2][2];
#pragma unroll
    for (int qs = 0; qs < 2; ++qs)
#pragma unroll
        for (int hf = 0; hf < 2; ++hf)
            qf[qs][hf] = *(const bf16x8*)&Qb[((qbase + w * 32 + qs * 16 + r) << 6) +
                                            hf * 32 + quad * 8];

    const u32x4 onesu = {0x3F803F80u, 0x3F803F80u, 0x3F803F80u, 0x3F803F80u};
    const bf16x8 vones = __builtin_bit_cast(bf16x8, onesu); // bf16 1.0 x8

    f32x4 o[2][4];
#pragma unroll
    for (int qs = 0; qs < 2; ++qs)
#pragma unroll
        for (int i = 0; i < 4; ++i) o[qs][i] = (f32x4){0.f, 0.f, 0.f, 0.f};
    f32x4 osum[2];
    osum[0] = (f32x4){0.f, 0.f, 0.f, 0.f};
    osum[1] = (f32x4){0.f, 0.f, 0.f, 0.f};

    auto stage = [&](int b, int kv0) {
#pragma unroll
        for (int ii = 0; ii < 2; ++ii) {
            const int chunk = w * 2 + ii;
            const int skr = (srl & 3) ^ ((chunk & 1) << 1) ^ ((chunk & 2) << 1);
            gl_lds16(Kb + ((size_t)(bh * 2048 + kv0 + chunk * 8 + srl) << 6) +
                         ((l & 7) ^ skr) * 8,
                     &lk[b][chunk * 512]);
            gl_lds16(Vt + (((size_t)(bh * 64 + chunk * 8 + srl)) << 11) + kv0 + sg * 8,
                     &lv[b][chunk * 512]);
        }
    };

    int Roff[4];
#pragma unroll
    for (int kt = 0; kt < 4; ++kt) {
        const int R = (kt & 1) * 32 + (r >> 2) * 8 + (kt >> 1) * 4 + (r & 3);
        Roff[kt] = R * 64 + g0;
    }

    auto readK = [&](int b, bf16x8 (&ka)[4], bf16x8 (&kb)[4]) {
        const u16* base = &lk[b][0];
#pragma unroll
        for (int kt = 0; kt < 4; ++kt) {
            ka[kt] = *(const bf16x8*)&base[Roff[kt]];
            kb[kt] = *(const bf16x8*)&base[Roff[kt] ^ 32];
        }
    };

    stage(0, 0);
    stage(1, 64);
    __syncthreads(); // tiles 0,1 resident

    bf16x8 kaE[4], kbE[4], kaO[4], kbO[4]; // even/odd iter K-frag sets
    readK(0, kaE, kbE);

    int cur = 0, nx1 = 1, nx2 = 2;

    auto body = [&](int t, bf16x8 (&kaP)[4], bf16x8 (&kbP)[4],
                    bf16x8 (&kaN)[4], bf16x8 (&kbN)[4]) {
        if (t + 2 < 32) stage(nx2, (t + 2) * 64); // DMA flies under compute
        bf16x8 vb[2][4];
#pragma unroll
        for (int h = 0; h < 2; ++h)
#pragma unroll
            for (int dt = 0; dt < 4; ++dt) {
                const int baseV = (dt * 2 + rhi) * 512 + rl * 64;
                vb[h][dt] = *(const bf16x8*)&lv[cur][baseV + ((h * 4 + quad) ^ rl) * 8];
            }
        // QK on PREFETCHED K-frags: starts immediately post-barrier
        bf16x4 pk4[2][4];
#pragma unroll
        for (int kt = 0; kt < 4; ++kt) {
#pragma unroll
            for (int qs = 0; qs < 2; ++qs) {
                f32x4 z = (f32x4){0.f, 0.f, 0.f, 0.f};
                __builtin_amdgcn_s_setprio(1);
                z = __builtin_amdgcn_mfma_f32_16x16x32_bf16(kaP[kt], qf[qs][0], z, 0, 0, 0);
                z = __builtin_amdgcn_mfma_f32_16x16x32_bf16(kbP[kt], qf[qs][1], z, 0, 0, 0);
                __builtin_amdgcn_s_setprio(0);
                bf16x4 pb;
                pb[0] = (__bf16)__builtin_amdgcn_exp2f(z[0]);
                pb[1] = (__bf16)__builtin_amdgcn_exp2f(z[1]);
                pb[2] = (__bf16)__builtin_amdgcn_exp2f(z[2]);
                pb[3] = (__bf16)__builtin_amdgcn_exp2f(z[3]);
                pk4[qs][kt] = pb;
            }
        }
        // prefetch NEXT iter's K-frags (tile t+1 drained at last barrier)
        if (t + 1 < 32) readK(nx1, kaN, kbN);
        // PV
        __builtin_amdgcn_s_setprio(1);
#pragma unroll
        for (int h = 0; h < 2; ++h) {
            const bf16x8 ap0 = __builtin_shufflevector(pk4[0][h], pk4[0][h + 2],
                                                       0, 1, 2, 3, 4, 5, 6, 7);
            const bf16x8 ap1 = __builtin_shufflevector(pk4[1][h], pk4[1][h + 2],
                                                       0, 1, 2, 3, 4, 5, 6, 7);
#pragma unroll
            for (int dt = 0; dt < 4; ++dt) {
                o[0][dt] = __builtin_amdgcn_mfma_f32_16x16x32_bf16(ap0, vb[h][dt],
                                                                  o[0][dt], 0, 0, 0);
                o[1][dt] = __builtin_amdgcn_mfma_f32_16x16x32_bf16(ap1, vb[h][dt],
                                                                  o[1][dt], 0, 0, 0);
            }
            osum[0] = __builtin_amdgcn_mfma_f32_16x16x32_bf16(ap0, vones, osum[0], 0, 0, 0);
            osum[1] = __builtin_amdgcn_mfma_f32_16x16x32_bf16(ap1, vones, osum[1], 0, 0, 0);
        }
        __builtin_amdgcn_s_setprio(0);

        __syncthreads(); // drains stage(t+2); tile t+1 already long-resident
        const int tmp = cur;
        cur = nx1;
        nx1 = nx2;
        nx2 = tmp;
    };

    for (int t = 0; t < 32; t += 2) {
        body(t, kaE, kbE, kaO, kbO);
        body(t + 1, kaO, kbO, kaE, kbE);
    }

    const int bb = bh >> 3, head = bh & 7;
#pragma unroll
    for (int qs = 0; qs < 2; ++qs) {
#pragma unroll
        for (int i = 0; i < 4; ++i) {
            const float inv = __builtin_amdgcn_rcpf(osum[qs][i]); // <=1 ulp, fine
            const int row = bb * 2048 + qt * 128 + w * 32 + qs * 16 + quad * 4 + i;
#pragma unroll
            for (int dt = 0; dt < 4; ++dt)
                attnb[(size_t)row * 512 + head * 64 + dt * 16 + r] =
                    f2bf(o[qs][dt][i] * inv);
        }
    }
}

// ---------------- launch ----------------
extern "C" void kernel_launch(void* const* d_in, const int* in_sizes, int n_in,
                              void* d_out, int out_size, void* d_ws, size_t ws_size,
                              hipStream_t stream) {
    const float *x = nullptr, *wq = nullptr, *bq = nullptr, *wp = nullptr, *bp = nullptr;
    for (int i = 0; i < n_in; ++i) {
        switch (in_sizes[i]) {
            case 4194304: x  = (const float*)d_in[i]; break;
            case 786432:  wq = (const float*)d_in[i]; break;
            case 1536:    bq = (const float*)d_in[i]; break;
            case 262144:  wp = (const float*)d_in[i]; break;
            case 512:     bp = (const float*)d_in[i]; break;
        }
    }
    if (!x || !wq || !bq || !wp || !bp) {
        x = (const float*)d_in[0]; wq = (const float*)d_in[1];
        bq = (const float*)d_in[2]; wp = (const float*)d_in[3];
        bp = (const float*)d_in[4];
    }
    float* out = (float*)d_out;

    // ws plan (ws = 256 MiB, confirmed by the harness's 256MiB re-poison
    // fill): attnb@0 (wqkvT aliases until attn), Qb@8M, Kb@16M, Vt@24M,
    // wprojT@32M (no alias -> producible up front). xbf in d_out until proj.
    char* ws = (char*)d_ws;
    u16* attnb  = (u16*)(ws + 0);
    u16* wqkvT  = (u16*)(ws + 0);
    u16* Qb     = (u16*)(ws + 8388608);
    u16* Kb     = (u16*)(ws + 16777216);
    u16* Vt     = (u16*)(ws + 25165824);
    u16* wprojT = (u16*)(ws + 33554432);
    u16* xbf    = (u16*)d_out;

    prep_k<<<dim3(4352), 256, 0, stream>>>(x, xbf, wq, wqkvT, wp, wprojT);
    gemm_bt_k<0, 128><<<dim3(64, 12), 256, 0, stream>>>(xbf, wqkvT, bq, Qb, Kb, Vt,
                                                        nullptr);
    attn_k<<<dim3(16, 32), 256, 0, stream>>>(Qb, Kb, Vt, attnb);
    gemm_bt_k<1, 64><<<dim3(64, 8), 256, 0, stream>>>(attnb, wprojT, bp, nullptr,
                                                      nullptr, nullptr, out);
}

// Round 14
// 148.567 us; speedup vs baseline: 1.0444x; 1.0181x over previous
//
#include <hip/hip_runtime.h>
#include <stdint.h>

typedef unsigned short u16;
typedef __attribute__((ext_vector_type(8))) __bf16 bf16x8;
typedef __attribute__((ext_vector_type(4))) __bf16 bf16x4;
typedef __attribute__((ext_vector_type(4))) float f32x4;
typedef __attribute__((ext_vector_type(2))) unsigned int u32x2;
typedef __attribute__((ext_vector_type(4))) unsigned int u32x4;

#define QSCALE 0.18033688011112042f /* (1/8) * log2(e) */

__device__ __forceinline__ u16 f2bf(float f) {
    uint32_t u = __builtin_bit_cast(uint32_t, f);
    u = (u + 0x7fffu + ((u >> 16) & 1u)) >> 16;
    return (u16)u;
}

// async global->LDS, 16B/lane; LDS dest = wave-uniform base + lane*16.
__device__ __forceinline__ void gl_lds16(const u16* g, u16* l) {
    __builtin_amdgcn_global_load_lds(
        (__attribute__((address_space(1))) uint32_t*)(g),
        (__attribute__((address_space(3))) uint32_t*)(l), 16, 0, 0);
}

// ---- fused prep (one launch, 3 jobs):
//   blocks [0,4096):      x fp32 -> bf16
//   blocks [4096,4288):   wqkv transpose-cvt (24x8 tiles over [512][1536])
//   blocks [4288,4352):   wp transpose-cvt   (8x8  tiles over [512][512])
__global__ __launch_bounds__(256) void prep_k(const float* __restrict__ xf,
                                              u16* __restrict__ xbf,
                                              const float* __restrict__ wq,
                                              u16* __restrict__ wqkvT,
                                              const float* __restrict__ wp,
                                              u16* __restrict__ wprojT) {
    __shared__ u16 t[64][65];
    const int b = blockIdx.x;
    const int tid = threadIdx.x;
    if (b < 4096) {
        const size_t v = (size_t)b * 256 + tid; // float4 index
        const f32x4 val = ((const f32x4*)xf)[v];
        u32x2 p;
        p.x = (uint32_t)f2bf(val.x) | ((uint32_t)f2bf(val.y) << 16);
        p.y = (uint32_t)f2bf(val.z) | ((uint32_t)f2bf(val.w) << 16);
        *(u32x2*)&xbf[v * 4] = p;
    } else {
        const bool isWq = (b < 4288);
        const int bb = isWq ? (b - 4096) : (b - 4288);
        const int nbx = isWq ? 24 : 8;
        const int C = isWq ? 1536 : 512;
        const float* src = isWq ? wq : wp;
        u16* dst = isWq ? wqkvT : wprojT;
        const int bx = (bb % nbx) << 6, by = (bb / nbx) << 6;
        const int tx = tid & 63, ty = tid >> 6; // 64 x 4
#pragma unroll
        for (int i = ty; i < 64; i += 4)
            t[i][tx] = f2bf(src[(size_t)(by + i) * C + bx + tx]);
        __syncthreads();
#pragma unroll
        for (int i = ty; i < 64; i += 4)
            dst[(size_t)(bx + i) * 512 + by + tx] = t[tx][i];
    }
}

// ---- m97-style MFMA GEMM (QKV), 2-phase pipelined, 128x128, BK=32
// (proven R10 config; frozen). EPI: LDS-bounce -> coalesced Q/K/Vt stores.
__global__ __launch_bounds__(256, 3) void gemm_qkv_k(
    const u16* __restrict__ A, const u16* __restrict__ Bt,
    const float* __restrict__ bias,
    u16* __restrict__ Qb, u16* __restrict__ Kb, u16* __restrict__ Vt) {
    constexpr int SSTG = 2 * 128 * 32 + 2 * 128 * 32; // u16 units
    constexpr int SEPI = 128 * 136;
    constexpr int SMEM = SSTG > SEPI ? SSTG : SEPI;
    __shared__ u16 smem[SMEM];
    u16* lA = smem;                // [2][128*32]
    u16* lB = smem + 2 * 128 * 32; // [2][128*32]

    const int tid = threadIdx.x;
    const int w = tid >> 6, l = tid & 63, quad = l >> 4, r = l & 15;
    const int tm = blockIdx.x << 7;
    const int tn = blockIdx.y << 7;
    const int wm = (w >> 1) << 6;
    const int wn = (w & 1) << 6;
    const int srow = l >> 2, sch = (l & 3) << 3;

    f32x4 acc[4][4];
#pragma unroll
    for (int i = 0; i < 4; ++i)
#pragma unroll
        for (int j = 0; j < 4; ++j) acc[i][j] = (f32x4){0.f, 0.f, 0.f, 0.f};

    auto stage = [&](int b, int kk) {
#pragma unroll
        for (int ii = 0; ii < 2; ++ii) {
            const int rowl = w * 32 + ii * 16; // wave-uniform
            gl_lds16(A + (size_t)(tm + rowl + srow) * 512 + kk + sch,
                     &lA[b * 4096 + rowl * 32]);
            gl_lds16(Bt + (size_t)(tn + rowl + srow) * 512 + kk + sch,
                     &lB[b * 4096 + rowl * 32]);
        }
    };

    stage(0, 0);
    __syncthreads(); // implicit vmcnt(0): tile 0 resident

    int cur = 0;
    for (int kk = 0; kk < 512; kk += 32) {
        if (kk + 32 < 512) stage(cur ^ 1, kk + 32); // in flight during compute
        bf16x8 af[4], bfr[4];
#pragma unroll
        for (int mi = 0; mi < 4; ++mi)
            af[mi] =
                *(const bf16x8*)&lA[cur * 4096 + (wm + mi * 16 + r) * 32 + quad * 8];
#pragma unroll
        for (int ni = 0; ni < 4; ++ni)
            bfr[ni] =
                *(const bf16x8*)&lB[cur * 4096 + (wn + ni * 16 + r) * 32 + quad * 8];
#pragma unroll
        for (int mi = 0; mi < 4; ++mi)
#pragma unroll
            for (int ni = 0; ni < 4; ++ni)
                acc[mi][ni] = __builtin_amdgcn_mfma_f32_16x16x32_bf16(
                    af[mi], bfr[ni], acc[mi][ni], 0, 0, 0);
        __syncthreads(); // drains next-tile loads (flew during MFMAs) + frag reads
        cur ^= 1;
    }

    // ---- LDS-bounce epilogue: coalesced Q/K/Vt stores ----
    const bool isV = (tn >= 1024);
    const bool isQ = (tn < 512);
#pragma unroll
    for (int ni = 0; ni < 4; ++ni) {
        const int nl = wn + ni * 16 + r;
        const float bv = bias[tn + nl];
#pragma unroll
        for (int mi = 0; mi < 4; ++mi)
#pragma unroll
            for (int i = 0; i < 4; ++i) {
                const int ml = wm + mi * 16 + quad * 4 + i;
                float v = acc[mi][ni][i] + bv;
                if (isQ) v *= QSCALE;
                const u16 hb = f2bf(v);
                if (isV)
                    smem[nl * 136 + ml] = hb; // transposed for t-contig rows
                else
                    smem[ml * 136 + nl] = hb;
            }
    }
    __syncthreads();
    const int tbb = tm >> 11, tt = tm & 2047;
    if (!isV) {
        u16* base = isQ ? Qb : Kb;
        const int mlr = l >> 3, ls = l & 7;
#pragma unroll
        for (int rg = 0; rg < 4; ++rg)
#pragma unroll
            for (int h = 0; h < 2; ++h) {
                const int ml = (w * 4 + rg) * 8 + mlr;
                const int head = ((tn + h * 64) >> 6) & 7;
                const int bh = tbb * 8 + head;
                const u32x4 dv = *(const u32x4*)&smem[ml * 136 + h * 64 + ls * 8];
                *(u32x4*)&base[((size_t)(bh * 2048 + tt + ml) << 6) + ls * 8] = dv;
            }
    } else {
        const int nlr = l >> 4, ls = l & 15;
#pragma unroll
        for (int j2 = 0; j2 < 8; ++j2) {
            const int nl = w * 32 + j2 * 4 + nlr;
            const int n = tn + nl;
            const int d = n & 63, head = (n >> 6) & 7;
            const int bh = tbb * 8 + head;
            const u32x4 dv = *(const u32x4*)&smem[nl * 136 + ls * 8];
            *(u32x4*)&Vt[((size_t)(bh * 64 + d) << 11) + tt + ls * 8] = dv;
        }
    }
}

// ---- proj GEMM (out = attnb @ wprojT^T + bias), BK=64: halves the
// barrier-drain count (16->8 K-steps) at UNCHANGED occupancy (48KB LDS ->
// 3 blocks/CU capacity, grid caps at 2 -- m132's BK-regression mechanism
// doesn't apply). 128B LDS rows would be a 16-way read conflict; fixed by
// the attn-proven row-XOR swizzle: stored(row,g) = data(row, g^(row&7))
// via pre-swizzled gl_lds16 SOURCE (rule #21), read at g^(r&7) ->
// 8 bank-groups x 2-way = free (m136). Measured 0 conflicts in attn.
__global__ __launch_bounds__(256, 3) void gemm_proj_k(
    const u16* __restrict__ A, const u16* __restrict__ Bt,
    const float* __restrict__ bias, float* __restrict__ OutF) {
    __shared__ u16 lA[2][128 * 64];
    __shared__ u16 lB[2][64 * 64];
    const int tid = threadIdx.x;
    const int w = tid >> 6, l = tid & 63, quad = l >> 4, r = l & 15;
    const int tm = blockIdx.x << 7;
    const int tn = blockIdx.y << 6;
    const int wm = w << 5; // 4 waves x 32 M-rows
    const int srl = l >> 3;
    const int sg8 = ((l & 7) ^ srl) << 3; // swizzled source granule (u16)
    const int rswz = r & 7;

    f32x4 acc[2][4];
#pragma unroll
    for (int i = 0; i < 2; ++i)
#pragma unroll
        for (int j = 0; j < 4; ++j) acc[i][j] = (f32x4){0.f, 0.f, 0.f, 0.f};

    auto stage = [&](int b, int kk) {
        // A: 16 chunks of 8 rows; wave w covers 4.
#pragma unroll
        for (int ii = 0; ii < 4; ++ii) {
            const int ck = w * 4 + ii;
            gl_lds16(A + (size_t)(tm + ck * 8 + srl) * 512 + kk + sg8,
                     &lA[b][ck * 512]);
        }
        // B: 8 chunks; wave w covers 2.
#pragma unroll
        for (int ii = 0; ii < 2; ++ii) {
            const int ck = w * 2 + ii;
            gl_lds16(Bt + (size_t)(tn + ck * 8 + srl) * 512 + kk + sg8,
                     &lB[b][ck * 512]);
        }
    };

    stage(0, 0);
    __syncthreads(); // implicit vmcnt(0): tile 0 resident

    int cur = 0;
    for (int kk = 0; kk < 512; kk += 64) {
        if (kk + 64 < 512) stage(cur ^ 1, kk + 64); // in flight during compute
        bf16x8 af[2][2], bfr[4][2];
#pragma unroll
        for (int kk2 = 0; kk2 < 2; ++kk2) {
            const int gsw = ((kk2 << 2) + quad) ^ rswz; // stored granule
#pragma unroll
            for (int mi = 0; mi < 2; ++mi)
                af[mi][kk2] =
                    *(const bf16x8*)&lA[cur][(wm + mi * 16 + r) * 64 + gsw * 8];
#pragma unroll
            for (int ni = 0; ni < 4; ++ni)
                bfr[ni][kk2] =
                    *(const bf16x8*)&lB[cur][(ni * 16 + r) * 64 + gsw * 8];
        }
#pragma unroll
        for (int mi = 0; mi < 2; ++mi)
#pragma unroll
            for (int ni = 0; ni < 4; ++ni)
#pragma unroll
                for (int kk2 = 0; kk2 < 2; ++kk2)
                    acc[mi][ni] = __builtin_amdgcn_mfma_f32_16x16x32_bf16(
                        af[mi][kk2], bfr[ni][kk2], acc[mi][ni], 0, 0, 0);
        __syncthreads(); // drains next-tile loads + frag reads
        cur ^= 1;
    }

#pragma unroll
    for (int ni = 0; ni < 4; ++ni) {
        const int n = tn + ni * 16 + r;
        const float bv = bias[n];
#pragma unroll
        for (int mi = 0; mi < 2; ++mi)
#pragma unroll
            for (int i = 0; i < 4; ++i) {
                const int m = tm + wm + mi * 16 + quad * 4 + i;
                OutF[(size_t)m * 512 + n] = acc[mi][ni][i] + bv;
            }
    }
}

// ---- MFMA flash attention v11 (frozen from R12/R13): 3 buffers, stage 2
// ahead, cross-barrier K-frag register prefetch, in-register P path, zero
// bank conflicts, XCD swizzle (each XCD owns 4 bh -> 2MB K/V L2-resident;
// measured FETCH 69.7 -> 12.3 MB).
__global__ __launch_bounds__(256, 2) void attn_k(
    const u16* __restrict__ Qb, const u16* __restrict__ Kb,
    const u16* __restrict__ Vt, u16* __restrict__ attnb) {
    __shared__ u16 lk[3][64 * 64];
    __shared__ u16 lv[3][64 * 64];
    const int tid = threadIdx.x;
    const int w = tid >> 6, l = tid & 63, quad = l >> 4, r = l & 15;
    // XCD swizzle: bh-chunk per XCD, qt fastest.
    const int bid = blockIdx.x + 16 * blockIdx.y; // [0,512)
    const int xcd = bid & 7, idx = bid >> 3;      // idx in [0,64)
    const int bh = xcd * 4 + (idx >> 4);
    const int qt = idx & 15;
    const size_t qbase = (size_t)bh * 2048 + qt * 128;
    const int srl = l >> 3;
    const int sg = (l & 7) ^ srl; // V staging swizzle

    const int rl = r & 7;
    const int rhi = r >> 3;
    const int skq = (r & 3) ^ (((r >> 2) & 1) << 1) ^ (((r >> 2) & 2) << 1);
    const int g0 = (quad ^ skq) << 3; // stored granule (u16 units)

    bf16x8 qf[2][2];
#pragma unroll
    for (int qs = 0; qs < 2; ++qs)
#pragma unroll
        for (int hf = 0; hf < 2; ++hf)
            qf[qs][hf] = *(const bf16x8*)&Qb[((qbase + w * 32 + qs * 16 + r) << 6) +
                                            hf * 32 + quad * 8];

    const u32x4 onesu = {0x3F803F80u, 0x3F803F80u, 0x3F803F80u, 0x3F803F80u};
    const bf16x8 vones = __builtin_bit_cast(bf16x8, onesu); // bf16 1.0 x8

    f32x4 o[2][4];
#pragma unroll
    for (int qs = 0; qs < 2; ++qs)
#pragma unroll
        for (int i = 0; i < 4; ++i) o[qs][i] = (f32x4){0.f, 0.f, 0.f, 0.f};
    f32x4 osum[2];
    osum[0] = (f32x4){0.f, 0.f, 0.f, 0.f};
    osum[1] = (f32x4){0.f, 0.f, 0.f, 0.f};

    auto stage = [&](int b, int kv0) {
#pragma unroll
        for (int ii = 0; ii < 2; ++ii) {
            const int chunk = w * 2 + ii;
            const int skr = (srl & 3) ^ ((chunk & 1) << 1) ^ ((chunk & 2) << 1);
            gl_lds16(Kb + ((size_t)(bh * 2048 + kv0 + chunk * 8 + srl) << 6) +
                         ((l & 7) ^ skr) * 8,
                     &lk[b][chunk * 512]);
            gl_lds16(Vt + (((size_t)(bh * 64 + chunk * 8 + srl)) << 11) + kv0 + sg * 8,
                     &lv[b][chunk * 512]);
        }
    };

    int Roff[4];
#pragma unroll
    for (int kt = 0; kt < 4; ++kt) {
        const int R = (kt & 1) * 32 + (r >> 2) * 8 + (kt >> 1) * 4 + (r & 3);
        Roff[kt] = R * 64 + g0;
    }

    auto readK = [&](int b, bf16x8 (&ka)[4], bf16x8 (&kb)[4]) {
        const u16* base = &lk[b][0];
#pragma unroll
        for (int kt = 0; kt < 4; ++kt) {
            ka[kt] = *(const bf16x8*)&base[Roff[kt]];
            kb[kt] = *(const bf16x8*)&base[Roff[kt] ^ 32];
        }
    };

    stage(0, 0);
    stage(1, 64);
    __syncthreads(); // tiles 0,1 resident

    bf16x8 kaE[4], kbE[4], kaO[4], kbO[4]; // even/odd iter K-frag sets
    readK(0, kaE, kbE);

    int cur = 0, nx1 = 1, nx2 = 2;

    auto body = [&](int t, bf16x8 (&kaP)[4], bf16x8 (&kbP)[4],
                    bf16x8 (&kaN)[4], bf16x8 (&kbN)[4]) {
        if (t + 2 < 32) stage(nx2, (t + 2) * 64); // DMA flies under compute
        bf16x8 vb[2][4];
#pragma unroll
        for (int h = 0; h < 2; ++h)
#pragma unroll
            for (int dt = 0; dt < 4; ++dt) {
                const int baseV = (dt * 2 + rhi) * 512 + rl * 64;
                vb[h][dt] = *(const bf16x8*)&lv[cur][baseV + ((h * 4 + quad) ^ rl) * 8];
            }
        // QK on PREFETCHED K-frags: starts immediately post-barrier
        bf16x4 pk4[2][4];
#pragma unroll
        for (int kt = 0; kt < 4; ++kt) {
#pragma unroll
            for (int qs = 0; qs < 2; ++qs) {
                f32x4 z = (f32x4){0.f, 0.f, 0.f, 0.f};
                __builtin_amdgcn_s_setprio(1);
                z = __builtin_amdgcn_mfma_f32_16x16x32_bf16(kaP[kt], qf[qs][0], z, 0, 0, 0);
                z = __builtin_amdgcn_mfma_f32_16x16x32_bf16(kbP[kt], qf[qs][1], z, 0, 0, 0);
                __builtin_amdgcn_s_setprio(0);
                bf16x4 pb;
                pb[0] = (__bf16)__builtin_amdgcn_exp2f(z[0]);
                pb[1] = (__bf16)__builtin_amdgcn_exp2f(z[1]);
                pb[2] = (__bf16)__builtin_amdgcn_exp2f(z[2]);
                pb[3] = (__bf16)__builtin_amdgcn_exp2f(z[3]);
                pk4[qs][kt] = pb;
            }
        }
        // prefetch NEXT iter's K-frags (tile t+1 drained at last barrier)
        if (t + 1 < 32) readK(nx1, kaN, kbN);
        // PV
        __builtin_amdgcn_s_setprio(1);
#pragma unroll
        for (int h = 0; h < 2; ++h) {
            const bf16x8 ap0 = __builtin_shufflevector(pk4[0][h], pk4[0][h + 2],
                                                       0, 1, 2, 3, 4, 5, 6, 7);
            const bf16x8 ap1 = __builtin_shufflevector(pk4[1][h], pk4[1][h + 2],
                                                       0, 1, 2, 3, 4, 5, 6, 7);
#pragma unroll
            for (int dt = 0; dt < 4; ++dt) {
                o[0][dt] = __builtin_amdgcn_mfma_f32_16x16x32_bf16(ap0, vb[h][dt],
                                                                  o[0][dt], 0, 0, 0);
                o[1][dt] = __builtin_amdgcn_mfma_f32_16x16x32_bf16(ap1, vb[h][dt],
                                                                  o[1][dt], 0, 0, 0);
            }
            osum[0] = __builtin_amdgcn_mfma_f32_16x16x32_bf16(ap0, vones, osum[0], 0, 0, 0);
            osum[1] = __builtin_amdgcn_mfma_f32_16x16x32_bf16(ap1, vones, osum[1], 0, 0, 0);
        }
        __builtin_amdgcn_s_setprio(0);

        __syncthreads(); // drains stage(t+2); tile t+1 already long-resident
        const int tmp = cur;
        cur = nx1;
        nx1 = nx2;
        nx2 = tmp;
    };

    for (int t = 0; t < 32; t += 2) {
        body(t, kaE, kbE, kaO, kbO);
        body(t + 1, kaO, kbO, kaE, kbE);
    }

    const int bb = bh >> 3, head = bh & 7;
#pragma unroll
    for (int qs = 0; qs < 2; ++qs) {
#pragma unroll
        for (int i = 0; i < 4; ++i) {
            const float inv = __builtin_amdgcn_rcpf(osum[qs][i]); // <=1 ulp, fine
            const int row = bb * 2048 + qt * 128 + w * 32 + qs * 16 + quad * 4 + i;
#pragma unroll
            for (int dt = 0; dt < 4; ++dt)
                attnb[(size_t)row * 512 + head * 64 + dt * 16 + r] =
                    f2bf(o[qs][dt][i] * inv);
        }
    }
}

// ---------------- launch ----------------
extern "C" void kernel_launch(void* const* d_in, const int* in_sizes, int n_in,
                              void* d_out, int out_size, void* d_ws, size_t ws_size,
                              hipStream_t stream) {
    const float *x = nullptr, *wq = nullptr, *bq = nullptr, *wp = nullptr, *bp = nullptr;
    for (int i = 0; i < n_in; ++i) {
        switch (in_sizes[i]) {
            case 4194304: x  = (const float*)d_in[i]; break;
            case 786432:  wq = (const float*)d_in[i]; break;
            case 1536:    bq = (const float*)d_in[i]; break;
            case 262144:  wp = (const float*)d_in[i]; break;
            case 512:     bp = (const float*)d_in[i]; break;
        }
    }
    if (!x || !wq || !bq || !wp || !bp) {
        x = (const float*)d_in[0]; wq = (const float*)d_in[1];
        bq = (const float*)d_in[2]; wp = (const float*)d_in[3];
        bp = (const float*)d_in[4];
    }
    float* out = (float*)d_out;

    // ws plan (ws = 256 MiB per the harness's re-poison fill): attnb@0
    // (wqkvT aliases until attn), Qb@8M, Kb@16M, Vt@24M, wprojT@32M.
    // xbf lives in d_out until proj overwrites it.
    char* ws = (char*)d_ws;
    u16* attnb  = (u16*)(ws + 0);
    u16* wqkvT  = (u16*)(ws + 0);
    u16* Qb     = (u16*)(ws + 8388608);
    u16* Kb     = (u16*)(ws + 16777216);
    u16* Vt     = (u16*)(ws + 25165824);
    u16* wprojT = (u16*)(ws + 33554432);
    u16* xbf    = (u16*)d_out;

    prep_k<<<dim3(4352), 256, 0, stream>>>(x, xbf, wq, wqkvT, wp, wprojT);
    gemm_qkv_k<<<dim3(64, 12), 256, 0, stream>>>(xbf, wqkvT, bq, Qb, Kb, Vt);
    attn_k<<<dim3(16, 32), 256, 0, stream>>>(Qb, Kb, Vt, attnb);
    gemm_proj_k<<<dim3(64, 8), 256, 0, stream>>>(attnb, wprojT, bp, out);
}